// Round 1
// baseline (7752.387 us; speedup 1.0000x reference)
//
#include <hip/hip_runtime.h>
#include <math.h>

// ---------------------------------------------------------------------------
// Aggre_social: fused graph-attention forward on MI355X (f32, VALU).
// Sizes: NU=NI=50000, NR=5, D=64, B=512, LS=32, LI=64.
// ---------------------------------------------------------------------------

#define NUU 50000
#define NII 50000
#define DD 64
#define BB 512
#define LSS 32
#define LII 64

static __device__ __forceinline__ bool mread(const void* p, long i, int mode) {
  if (mode == 0) return ((const int*)p)[i] != 0;            // int32 storage
  if (mode == 2) return ((const float*)p)[i] != 0.0f;       // f32 storage
  return ((const unsigned char*)p)[i] != 0;                 // byte storage
}

static __device__ __forceinline__ float wsum(float v) {
#pragma unroll
  for (int s = 1; s < 64; s <<= 1) v += __shfl_xor(v, s);
  return v;
}
static __device__ __forceinline__ float wmax(float v) {
#pragma unroll
  for (int s = 1; s < 64; s <<= 1) v = fmaxf(v, __shfl_xor(v, s));
  return v;
}

// ---------------------------------------------------------------------------
// K0: detect boolean-mask storage format. flag: 0=int32, 1=byte, 2=float32.
// ---------------------------------------------------------------------------
__global__ void detect_mask_kernel(const unsigned int* __restrict__ sm,
                                   int* __restrict__ flag) {
  __shared__ int notInt, notFloat;
  if (threadIdx.x == 0) { notInt = 0; notFloat = 0; }
  __syncthreads();
  int ni = 0, nf = 0;
  for (int i = threadIdx.x; i < 4096; i += 256) {
    unsigned int x = sm[i];
    if (x > 1u) ni = 1;
    if (x != 0u && x != 0x3F800000u) nf = 1;
  }
  if (ni) atomicOr(&notInt, 1);
  if (nf) atomicOr(&notFloat, 1);
  __syncthreads();
  if (threadIdx.x == 0) flag[0] = notInt ? (notFloat ? 1 : 2) : 0;
}

// ---------------------------------------------------------------------------
// K1: RW1g[5][64] = rating_w @ W1b + i_ln1_b   (W1b = rows 64..127 of i_ln1_w)
// launch <<<1, 320>>>
// ---------------------------------------------------------------------------
__global__ void pre_rw_kernel(const float* __restrict__ rating_w,
                              const float* __restrict__ w1,
                              const float* __restrict__ b1,
                              float* __restrict__ RW1g) {
  const int r = threadIdx.x >> 6;
  const int c = threadIdx.x & 63;
  float acc = b1[c];
  for (int k = 0; k < 64; ++k)
    acc = fmaf(rating_w[r * 64 + k], w1[(64 + k) * 64 + c], acc);
  RW1g[r * 64 + c] = acc;
}

// ---------------------------------------------------------------------------
// K2: xbase[50000][64] = item_w @ W1a   (W1a = rows 0..63 of i_ln1_w, no bias)
// 32 rows per workgroup.
// ---------------------------------------------------------------------------
__global__ __launch_bounds__(256, 4)
void pre_xbase_kernel(const float* __restrict__ item_w,
                      const float* __restrict__ w1,
                      float* __restrict__ xbase) {
  __shared__ float sT[32][64];
  const int tid = threadIdx.x, lane = tid & 63, w = tid >> 6;
  const long r0 = (long)blockIdx.x * 32;
  for (int i = tid; i < 32 * 64; i += 256) {
    int r = i >> 6, col = i & 63;
    long gr = r0 + r;
    sT[r][col] = (gr < NII) ? item_w[gr * 64 + col] : 0.0f;
  }
  __syncthreads();
  float acc[8];
#pragma unroll
  for (int r = 0; r < 8; ++r) acc[r] = 0.0f;
  for (int k = 0; k < 64; k += 4) {
    float wv[4];
#pragma unroll
    for (int q = 0; q < 4; ++q) wv[q] = w1[(k + q) * 64 + lane];
#pragma unroll
    for (int r = 0; r < 8; ++r) {
      const float4 xv = *(const float4*)(&sT[w * 8 + r][k]);
      acc[r] = fmaf(xv.x, wv[0], acc[r]);
      acc[r] = fmaf(xv.y, wv[1], acc[r]);
      acc[r] = fmaf(xv.z, wv[2], acc[r]);
      acc[r] = fmaf(xv.w, wv[3], acc[r]);
    }
  }
#pragma unroll
  for (int r = 0; r < 8; ++r) {
    long gr = r0 + w * 8 + r;
    if (gr < NII) xbase[gr * 64 + lane] = acc[r];
  }
}

// ---------------------------------------------------------------------------
// K3: item_final for all instances.
//   inst <  512          : self user nodes[inst]          -> hIbuf[inst]
//   inst >= 512          : neighbor (b,l), b=(inst-512)/32, l=(inst-512)%32;
//                          skipped when social_mask invalid.
// ---------------------------------------------------------------------------
__global__ __launch_bounds__(256, 4)
void item_final_kernel(const float* __restrict__ user_w,
                       const float* __restrict__ xbase,
                       const float* __restrict__ RW1g,
                       const float* __restrict__ A1w, const float* __restrict__ A1b,
                       const float* __restrict__ A2w, const float* __restrict__ A2b,
                       const float* __restrict__ A3w, const float* __restrict__ A3b,
                       const float* __restrict__ W2w, const float* __restrict__ W2b,
                       const float* __restrict__ W3w, const float* __restrict__ W3b,
                       const int* __restrict__ nodes,
                       const int* __restrict__ social_hist,
                       const void* __restrict__ social_mask,
                       const int* __restrict__ item_hist,
                       const int* __restrict__ rating_hist,
                       const void* __restrict__ item_mask,
                       const int* __restrict__ flagp,
                       float* __restrict__ hIbuf) {
  const int tid = threadIdx.x, lane = tid & 63, w = tid >> 6;
  const int mode = flagp[0];
  const int inst = blockIdx.x;
  long uid;
  if (inst < BB) {
    uid = nodes[inst];
  } else {
    int t = inst - BB;
    int b = t >> 5, l = t & 31;
    long mi = (long)nodes[b] * LSS + l;
    if (!mread(social_mask, mi, mode)) return;  // uniform: whole block exits
    uid = social_hist[mi];
  }

  __shared__ float uvec[64], uA1[64], logit[64], alpha[64], hvec[64];
  __shared__ float part[4][64];
  __shared__ float xls[64][64];
  __shared__ float h1ls[64][64];
  __shared__ int cih[64], crt[64];
  __shared__ int nact_s;

  if (w == 0) {
    long base = uid * 64;
    bool m = mread(item_mask, base + lane, mode);
    unsigned long long bal = __ballot(m);
    int pos = __popcll(bal & ((1ull << lane) - 1ull));
    if (m) {
      cih[pos] = item_hist[base + lane];
      crt[pos] = rating_hist[base + lane];
    }
    if (lane == 0) nact_s = (int)__popcll(bal);
  } else if (w == 1) {
    uvec[lane] = user_w[uid * 64 + lane];
  }
  __syncthreads();
  const int nact = nact_s;

  // uA1[c] = b_att1[c] + sum_k u[k]*A1[64+k][c]  (partials) ; X gather.
  {
    float acc = 0.0f;
#pragma unroll
    for (int kk = 0; kk < 16; ++kk) {
      int k = w * 16 + kk;
      acc = fmaf(uvec[k], A1w[(64 + k) * 64 + lane], acc);
    }
    part[w][lane] = acc;
  }
  for (int j = w; j < nact; j += 4) {
    long it = cih[j];
    int rt = crt[j];
    float v = xbase[it * 64 + lane] + RW1g[rt * 64 + lane];
    xls[j][lane] = fmaxf(v, 0.0f);  // x = relu([item;rating]@W1 + b1)
  }
  __syncthreads();
  if (tid < 64)
    uA1[tid] = part[0][tid] + part[1][tid] + part[2][tid] + part[3][tid] + A1b[tid];
  __syncthreads();

  const int nch = (nact > 32) ? 2 : 1;

  // att1: h1[j] = relu(uA1 + x[j] @ A1a)
  {
    const float base = uA1[lane];
    for (int ch = 0; ch < nch; ++ch) {
      const int j0 = w + 32 * ch;
      if (j0 < nact) {
        float acc[8];
#pragma unroll
        for (int r = 0; r < 8; ++r) acc[r] = base;
        for (int k = 0; k < 64; k += 4) {
          float wv[4];
#pragma unroll
          for (int q = 0; q < 4; ++q) wv[q] = A1w[(k + q) * 64 + lane];
#pragma unroll
          for (int r = 0; r < 8; ++r) {
            const float4 xv = *(const float4*)(&xls[j0 + 4 * r][k]);
            acc[r] = fmaf(xv.x, wv[0], acc[r]);
            acc[r] = fmaf(xv.y, wv[1], acc[r]);
            acc[r] = fmaf(xv.z, wv[2], acc[r]);
            acc[r] = fmaf(xv.w, wv[3], acc[r]);
          }
        }
#pragma unroll
        for (int r = 0; r < 8; ++r) {
          int j = j0 + 4 * r;
          if (j < nact) h1ls[j][lane] = fmaxf(acc[r], 0.0f);
        }
      }
    }
  }
  __syncthreads();

  // att2 + logit: h2 = relu(h1 @ A2 + b2); logit = h2 . a3 + b3
  {
    const float bA2 = A2b[lane];
    const float a3v = A3w[lane];
    const float a3b0 = A3b[0];
    for (int ch = 0; ch < nch; ++ch) {
      const int j0 = w + 32 * ch;
      if (j0 < nact) {
        float acc[8];
#pragma unroll
        for (int r = 0; r < 8; ++r) acc[r] = bA2;
        for (int k = 0; k < 64; k += 4) {
          float wv[4];
#pragma unroll
          for (int q = 0; q < 4; ++q) wv[q] = A2w[(k + q) * 64 + lane];
#pragma unroll
          for (int r = 0; r < 8; ++r) {
            const float4 hv = *(const float4*)(&h1ls[j0 + 4 * r][k]);
            acc[r] = fmaf(hv.x, wv[0], acc[r]);
            acc[r] = fmaf(hv.y, wv[1], acc[r]);
            acc[r] = fmaf(hv.z, wv[2], acc[r]);
            acc[r] = fmaf(hv.w, wv[3], acc[r]);
          }
        }
#pragma unroll
        for (int r = 0; r < 8; ++r) {
          int j = j0 + 4 * r;
          if (j < nact) {
            float p = fmaxf(acc[r], 0.0f) * a3v;
            p = wsum(p);
            if (lane == 0) logit[j] = p + a3b0;
          }
        }
      }
    }
  }
  __syncthreads();

  // softmax over active rows (wave 0)
  if (w == 0) {
    float lv = (lane < nact) ? logit[lane] : -1e30f;
    float mx = wmax(lv);
    float e = (lane < nact) ? __expf(lv - mx) : 0.0f;
    float s = wsum(e);
    alpha[lane] = e / s;
  }
  __syncthreads();

  // hI = sum_j alpha[j] * x[j]
  {
    float acc = 0.0f;
    for (int j = w; j < nact; j += 4) acc = fmaf(alpha[j], xls[j][lane], acc);
    part[w][lane] = acc;
  }
  __syncthreads();
  if (tid < 64) hvec[tid] = part[0][tid] + part[1][tid] + part[2][tid] + part[3][tid];
  __syncthreads();

  // hI2 = relu(hI @ i_ln2 + b)   (reuse logit[] as hI2 storage)
  {
    float acc = 0.0f;
#pragma unroll
    for (int kk = 0; kk < 16; ++kk) {
      int k = w * 16 + kk;
      acc = fmaf(hvec[k], W2w[k * 64 + lane], acc);
    }
    part[w][lane] = acc;
  }
  __syncthreads();
  if (tid < 64)
    logit[tid] = fmaxf(part[0][tid] + part[1][tid] + part[2][tid] + part[3][tid] + W2b[tid], 0.0f);
  __syncthreads();

  // out = relu([u ; hI2] @ i_ln3 + b)
  {
    float acc = 0.0f;
#pragma unroll
    for (int kk = 0; kk < 32; ++kk) {
      int k = w * 32 + kk;
      float xv = (k < 64) ? uvec[k] : logit[k - 64];
      acc = fmaf(xv, W3w[k * 64 + lane], acc);
    }
    part[w][lane] = acc;
  }
  __syncthreads();
  if (tid < 64)
    hIbuf[(long)inst * 64 + tid] =
        fmaxf(part[0][tid] + part[1][tid] + part[2][tid] + part[3][tid] + W3b[tid], 0.0f);
}

// ---------------------------------------------------------------------------
// K4: social aggregation + final MLP, one block per batch element.
// ---------------------------------------------------------------------------
__global__ __launch_bounds__(256, 4)
void social_kernel(const float* __restrict__ user_w,
                   const float* __restrict__ hIbuf,
                   const float* __restrict__ A1w, const float* __restrict__ A1b,
                   const float* __restrict__ A2w, const float* __restrict__ A2b,
                   const float* __restrict__ A3w, const float* __restrict__ A3b,
                   const float* __restrict__ L1w, const float* __restrict__ L1b,
                   const float* __restrict__ L2w, const float* __restrict__ L2b,
                   const float* __restrict__ L3w, const float* __restrict__ L3b,
                   const int* __restrict__ nodes,
                   const void* __restrict__ social_mask,
                   const int* __restrict__ flagp,
                   float* __restrict__ out) {
  const int tid = threadIdx.x, lane = tid & 63, w = tid >> 6;
  const int mode = flagp[0];
  const int b = blockIdx.x;
  const long uid = nodes[b];

  __shared__ float uvec[64], uA1[64], selfv[64], vecA[64], vecB[64];
  __shared__ float logit[32], beta[32];
  __shared__ float part[4][64];
  __shared__ float hv[32][64];
  __shared__ float h1[32][64];
  __shared__ int cslot[32];
  __shared__ int nval_s;

  if (w == 0) {
    bool m = false;
    if (lane < 32) m = mread(social_mask, uid * LSS + lane, mode);
    unsigned long long bal = __ballot(m);
    int pos = __popcll(bal & ((1ull << lane) - 1ull));
    if (m) cslot[pos] = lane;
    if (lane == 0) nval_s = (int)__popcll(bal);
  } else if (w == 1) {
    uvec[lane] = user_w[uid * 64 + lane];
  } else if (w == 2) {
    selfv[lane] = hIbuf[(long)b * 64 + lane];
  }
  __syncthreads();
  const int nval = nval_s;

  // uA1s partial + stage neighbor hI rows
  {
    float acc = 0.0f;
#pragma unroll
    for (int kk = 0; kk < 16; ++kk) {
      int k = w * 16 + kk;
      acc = fmaf(uvec[k], A1w[(64 + k) * 64 + lane], acc);
    }
    part[w][lane] = acc;
  }
  for (int j = w; j < nval; j += 4) {
    int l = cslot[j];
    hv[j][lane] = hIbuf[(512L + (long)b * 32 + l) * 64 + lane];
  }
  __syncthreads();
  if (tid < 64)
    uA1[tid] = part[0][tid] + part[1][tid] + part[2][tid] + part[3][tid] + A1b[tid];
  __syncthreads();

  // att1
  {
    const float base = uA1[lane];
    if (w < nval) {
      float acc[8];
#pragma unroll
      for (int r = 0; r < 8; ++r) acc[r] = base;
      for (int k = 0; k < 64; k += 4) {
        float wv[4];
#pragma unroll
        for (int q = 0; q < 4; ++q) wv[q] = A1w[(k + q) * 64 + lane];
#pragma unroll
        for (int r = 0; r < 8; ++r) {
          const float4 xv = *(const float4*)(&hv[w + 4 * r][k]);
          acc[r] = fmaf(xv.x, wv[0], acc[r]);
          acc[r] = fmaf(xv.y, wv[1], acc[r]);
          acc[r] = fmaf(xv.z, wv[2], acc[r]);
          acc[r] = fmaf(xv.w, wv[3], acc[r]);
        }
      }
#pragma unroll
      for (int r = 0; r < 8; ++r) {
        int j = w + 4 * r;
        if (j < nval) h1[j][lane] = fmaxf(acc[r], 0.0f);
      }
    }
  }
  __syncthreads();

  // att2 + logit
  {
    const float bA2 = A2b[lane];
    const float a3v = A3w[lane];
    const float a3b0 = A3b[0];
    if (w < nval) {
      float acc[8];
#pragma unroll
      for (int r = 0; r < 8; ++r) acc[r] = bA2;
      for (int k = 0; k < 64; k += 4) {
        float wv[4];
#pragma unroll
        for (int q = 0; q < 4; ++q) wv[q] = A2w[(k + q) * 64 + lane];
#pragma unroll
        for (int r = 0; r < 8; ++r) {
          const float4 xv = *(const float4*)(&h1[w + 4 * r][k]);
          acc[r] = fmaf(xv.x, wv[0], acc[r]);
          acc[r] = fmaf(xv.y, wv[1], acc[r]);
          acc[r] = fmaf(xv.z, wv[2], acc[r]);
          acc[r] = fmaf(xv.w, wv[3], acc[r]);
        }
      }
#pragma unroll
      for (int r = 0; r < 8; ++r) {
        int j = w + 4 * r;
        if (j < nval) {
          float p = fmaxf(acc[r], 0.0f) * a3v;
          p = wsum(p);
          if (lane == 0) logit[j] = p + a3b0;
        }
      }
    }
  }
  __syncthreads();

  if (w == 0) {
    float lv = (lane < nval) ? logit[lane] : -1e30f;
    float mx = wmax(lv);
    float e = (lane < nval) ? __expf(lv - mx) : 0.0f;
    float s = wsum(e);
    if (lane < 32) beta[lane] = e / s;
  }
  __syncthreads();

  // hS = sum_j beta[j] * hv[j]
  {
    float acc = 0.0f;
    for (int j = w; j < nval; j += 4) acc = fmaf(beta[j], hv[j][lane], acc);
    part[w][lane] = acc;
  }
  __syncthreads();
  if (tid < 64) vecA[tid] = part[0][tid] + part[1][tid] + part[2][tid] + part[3][tid];
  __syncthreads();

  // hS = relu(hS @ s_ln1 + b)
  {
    float acc = 0.0f;
#pragma unroll
    for (int kk = 0; kk < 16; ++kk) {
      int k = w * 16 + kk;
      acc = fmaf(vecA[k], L1w[k * 64 + lane], acc);
    }
    part[w][lane] = acc;
  }
  __syncthreads();
  if (tid < 64)
    vecB[tid] = fmaxf(part[0][tid] + part[1][tid] + part[2][tid] + part[3][tid] + L1b[tid], 0.0f);
  __syncthreads();

  // f = relu([hI_self ; hS] @ s_ln2 + b)
  {
    float acc = 0.0f;
#pragma unroll
    for (int kk = 0; kk < 32; ++kk) {
      int k = w * 32 + kk;
      float xv = (k < 64) ? selfv[k] : vecB[k - 64];
      acc = fmaf(xv, L2w[k * 64 + lane], acc);
    }
    part[w][lane] = acc;
  }
  __syncthreads();
  if (tid < 64)
    vecA[tid] = fmaxf(part[0][tid] + part[1][tid] + part[2][tid] + part[3][tid] + L2b[tid], 0.0f);
  __syncthreads();

  // out = relu(f @ s_ln3 + b)
  {
    float acc = 0.0f;
#pragma unroll
    for (int kk = 0; kk < 16; ++kk) {
      int k = w * 16 + kk;
      acc = fmaf(vecA[k], L3w[k * 64 + lane], acc);
    }
    part[w][lane] = acc;
  }
  __syncthreads();
  if (tid < 64)
    out[(long)b * 64 + tid] =
        fmaxf(part[0][tid] + part[1][tid] + part[2][tid] + part[3][tid] + L3b[tid], 0.0f);
}

// ---------------------------------------------------------------------------
extern "C" void kernel_launch(void* const* d_in, const int* in_sizes, int n_in,
                              void* d_out, int out_size, void* d_ws, size_t ws_size,
                              hipStream_t stream) {
  const float* user_w   = (const float*)d_in[0];
  const float* item_w   = (const float*)d_in[1];
  const float* rating_w = (const float*)d_in[2];
  const float* i_ln1_w  = (const float*)d_in[3];
  const float* i_ln1_b  = (const float*)d_in[4];
  const float* i_ln2_w  = (const float*)d_in[5];
  const float* i_ln2_b  = (const float*)d_in[6];
  const float* i_ln3_w  = (const float*)d_in[7];
  const float* i_ln3_b  = (const float*)d_in[8];
  const float* i_att1_w = (const float*)d_in[9];
  const float* i_att1_b = (const float*)d_in[10];
  const float* i_att2_w = (const float*)d_in[11];
  const float* i_att2_b = (const float*)d_in[12];
  const float* i_att3_w = (const float*)d_in[13];
  const float* i_att3_b = (const float*)d_in[14];
  const float* s_ln1_w  = (const float*)d_in[15];
  const float* s_ln1_b  = (const float*)d_in[16];
  const float* s_ln2_w  = (const float*)d_in[17];
  const float* s_ln2_b  = (const float*)d_in[18];
  const float* s_ln3_w  = (const float*)d_in[19];
  const float* s_ln3_b  = (const float*)d_in[20];
  const float* s_att1_w = (const float*)d_in[21];
  const float* s_att1_b = (const float*)d_in[22];
  const float* s_att2_w = (const float*)d_in[23];
  const float* s_att2_b = (const float*)d_in[24];
  const float* s_att3_w = (const float*)d_in[25];
  const float* s_att3_b = (const float*)d_in[26];
  const int*  nodes       = (const int*)d_in[27];
  const int*  social_hist = (const int*)d_in[28];
  const void* social_mask = d_in[29];
  const int*  item_hist   = (const int*)d_in[30];
  const int*  rating_hist = (const int*)d_in[31];
  const void* item_mask   = d_in[32];

  char* ws = (char*)d_ws;
  int*   flag  = (int*)ws;                                        // 256 B
  float* hIbuf = (float*)(ws + 256);                              // 16896*64*4
  float* xbase = (float*)(ws + 256 + 16896L * 64 * 4);            // 50000*64*4
  float* RW1g  = (float*)(ws + 256 + 16896L * 64 * 4 + 50000L * 64 * 4);  // 5*64*4

  detect_mask_kernel<<<1, 256, 0, stream>>>((const unsigned int*)social_mask, flag);
  pre_rw_kernel<<<1, 320, 0, stream>>>(rating_w, i_ln1_w, i_ln1_b, RW1g);
  pre_xbase_kernel<<<(NII + 31) / 32, 256, 0, stream>>>(item_w, i_ln1_w, xbase);
  item_final_kernel<<<BB + BB * LSS, 256, 0, stream>>>(
      user_w, xbase, RW1g,
      i_att1_w, i_att1_b, i_att2_w, i_att2_b, i_att3_w, i_att3_b,
      i_ln2_w, i_ln2_b, i_ln3_w, i_ln3_b,
      nodes, social_hist, social_mask, item_hist, rating_hist, item_mask,
      flag, hIbuf);
  social_kernel<<<BB, 256, 0, stream>>>(
      user_w, hIbuf,
      s_att1_w, s_att1_b, s_att2_w, s_att2_b, s_att3_w, s_att3_b,
      s_ln1_w, s_ln1_b, s_ln2_w, s_ln2_b, s_ln3_w, s_ln3_b,
      nodes, social_mask, flag, (float*)d_out);
}

// Round 2
// 619.509 us; speedup vs baseline: 12.5138x; 12.5138x over previous
//
#include <hip/hip_runtime.h>
#include <math.h>

// ---------------------------------------------------------------------------
// Aggre_social on MI355X — round 2: LDS-resident weights + batched instances.
// Sizes: NU=NI=50000, NR=5, D=64, B=512, LS=32, LI=64. NT = 512 + 512*32.
// ---------------------------------------------------------------------------

#define NII 50000
#define BB 512
#define LSS 32
#define NT 16896   // 512 self + 16384 neighbor instances

static __device__ __forceinline__ bool mread(const void* p, long i, int mode) {
  if (mode == 0) return ((const int*)p)[i] != 0;       // int32 storage
  if (mode == 2) return ((const float*)p)[i] != 0.0f;  // f32 storage
  return ((const unsigned char*)p)[i] != 0;            // byte storage
}

static __device__ __forceinline__ float wsum(float v) {
#pragma unroll
  for (int s = 1; s < 64; s <<= 1) v += __shfl_xor(v, s);
  return v;
}
static __device__ __forceinline__ float wmax(float v) {
#pragma unroll
  for (int s = 1; s < 64; s <<= 1) v = fmaxf(v, __shfl_xor(v, s));
  return v;
}

// ---------------------------------------------------------------------------
// K0: detect boolean-mask storage. flag: 0=int32, 1=byte, 2=float32.
// ---------------------------------------------------------------------------
__global__ void detect_mask_kernel(const unsigned int* __restrict__ sm,
                                   int* __restrict__ flag) {
  __shared__ int notInt, notFloat;
  if (threadIdx.x == 0) { notInt = 0; notFloat = 0; }
  __syncthreads();
  int ni = 0, nf = 0;
  for (int i = threadIdx.x; i < 4096; i += 256) {
    unsigned int x = sm[i];
    if (x > 1u) ni = 1;
    if (x != 0u && x != 0x3F800000u) nf = 1;
  }
  if (ni) atomicOr(&notInt, 1);
  if (nf) atomicOr(&notFloat, 1);
  __syncthreads();
  if (threadIdx.x == 0) flag[0] = notInt ? (notFloat ? 1 : 2) : 0;
}

// ---------------------------------------------------------------------------
// K1: RW1g[5][64] = rating_w @ W1[64:128] + i_ln1_b.   <<<1,320>>>
// ---------------------------------------------------------------------------
__global__ void pre_rw_kernel(const float* __restrict__ rating_w,
                              const float* __restrict__ w1,
                              const float* __restrict__ b1,
                              float* __restrict__ RW1g) {
  const int r = threadIdx.x >> 6;
  const int c = threadIdx.x & 63;
  float acc = b1[c];
  for (int k = 0; k < 64; ++k)
    acc = fmaf(rating_w[r * 64 + k], w1[(64 + k) * 64 + c], acc);
  RW1g[r * 64 + c] = acc;
}

// ---------------------------------------------------------------------------
// K2: xbase[50000][64] = item_w @ W1[0:64]  (weights LDS-staged).
// ---------------------------------------------------------------------------
__global__ __launch_bounds__(256, 2)
void pre_xbase_kernel(const float* __restrict__ item_w,
                      const float* __restrict__ w1,
                      float* __restrict__ xbase) {
  __shared__ float sW[64][64];
  __shared__ float sT[32][64];
  const int tid = threadIdx.x, lane = tid & 63, w = tid >> 6;
  for (int i = tid; i < 4096; i += 256) sW[i >> 6][i & 63] = w1[i];
  const long r0 = (long)blockIdx.x * 32;
  for (int i = tid; i < 2048; i += 256) {
    int r = i >> 6, c = i & 63;
    long gr = r0 + r;
    sT[r][c] = (gr < NII) ? item_w[gr * 64 + c] : 0.0f;
  }
  __syncthreads();
  float acc[8];
#pragma unroll
  for (int r = 0; r < 8; ++r) acc[r] = 0.0f;
  for (int k = 0; k < 64; k += 4) {
    float wv0 = sW[k][lane], wv1 = sW[k + 1][lane];
    float wv2 = sW[k + 2][lane], wv3 = sW[k + 3][lane];
#pragma unroll
    for (int r = 0; r < 8; ++r) {
      const float4 xv = *(const float4*)(&sT[w * 8 + r][k]);
      acc[r] = fmaf(xv.x, wv0, acc[r]);
      acc[r] = fmaf(xv.y, wv1, acc[r]);
      acc[r] = fmaf(xv.z, wv2, acc[r]);
      acc[r] = fmaf(xv.w, wv3, acc[r]);
    }
  }
#pragma unroll
  for (int r = 0; r < 8; ++r) {
    long gr = r0 + w * 8 + r;
    if (gr < NII) xbase[gr * 64 + lane] = acc[r];
  }
}

// ---------------------------------------------------------------------------
// K3: compact active instance list.  <<<66,256>>>
//   inst < 512: self (always active), uid = nodes[inst]
//   else: neighbor (b,l); active iff social_mask[nodes[b],l]
// ---------------------------------------------------------------------------
__global__ void build_active_kernel(const int* __restrict__ nodes,
                                    const int* __restrict__ social_hist,
                                    const void* __restrict__ social_mask,
                                    const int* __restrict__ flagp,
                                    int* __restrict__ counter,
                                    int* __restrict__ list,
                                    int* __restrict__ aUid) {
  const int t = blockIdx.x * 256 + threadIdx.x;
  if (t >= NT) return;
  const int mode = flagp[0];
  int uid;
  bool active;
  if (t < BB) {
    active = true;
    uid = nodes[t];
  } else {
    int nb = t - BB;
    int b = nb >> 5, l = nb & 31;
    long mi = (long)nodes[b] * LSS + l;
    active = mread(social_mask, mi, mode);
    uid = active ? social_hist[mi] : 0;
  }
  if (active) {
    int pos = atomicAdd(counter, 1);
    list[pos] = t;
    aUid[pos] = uid;
  }
}

// ---------------------------------------------------------------------------
// K4: uA1buf[idx] = user_w[aUid[idx]] @ A1w[64:128] + A1b.   64 rows / block.
// ---------------------------------------------------------------------------
__global__ __launch_bounds__(256, 2)
void uA1_kernel(const float* __restrict__ user_w,
                const float* __restrict__ A1w, const float* __restrict__ A1b,
                const int* __restrict__ aUid, const int* __restrict__ nActp,
                float* __restrict__ uA1buf) {
  const int tid = threadIdx.x, lane = tid & 63, w = tid >> 6;
  const int i0 = blockIdx.x * 64;
  const int nA = nActp[0];
  if (i0 >= nA) return;
  __shared__ float sW[64][64], sU[64][64];
  __shared__ float sb[64];
  __shared__ int sUid[64];
  for (int i = tid; i < 4096; i += 256) sW[i >> 6][i & 63] = A1w[4096 + i];
  if (tid < 64) {
    sb[tid] = A1b[tid];
    sUid[tid] = (i0 + tid < nA) ? aUid[i0 + tid] : 0;
  }
  __syncthreads();
  for (int i = tid; i < 4096; i += 256) {
    int r = i >> 6, c = i & 63;
    sU[r][c] = user_w[(long)sUid[r] * 64 + c];
  }
  __syncthreads();
  float acc[16];
#pragma unroll
  for (int r = 0; r < 16; ++r) acc[r] = sb[lane];
  for (int k = 0; k < 64; k += 4) {
    float wv0 = sW[k][lane], wv1 = sW[k + 1][lane];
    float wv2 = sW[k + 2][lane], wv3 = sW[k + 3][lane];
#pragma unroll
    for (int r = 0; r < 16; ++r) {
      const float4 xv = *(const float4*)(&sU[w * 16 + r][k]);
      acc[r] = fmaf(xv.x, wv0, acc[r]);
      acc[r] = fmaf(xv.y, wv1, acc[r]);
      acc[r] = fmaf(xv.z, wv2, acc[r]);
      acc[r] = fmaf(xv.w, wv3, acc[r]);
    }
  }
#pragma unroll
  for (int r = 0; r < 16; ++r) {
    int row = i0 + w * 16 + r;
    if (row < nA) uA1buf[(long)row * 64 + lane] = acc[r];
  }
}

// ---------------------------------------------------------------------------
// K5: attention core. 512 blocks x 256 thr, ~17 instances each.
// LDS ~60KB -> 2 blocks/CU. Streams sA1a/sA2 from LDS; att1->att2 fused per
// 8-row chunk (h1 lives in per-wave 8x64 buffer).
// ---------------------------------------------------------------------------
__global__ __launch_bounds__(256, 2)
void core_attn_kernel(const float* __restrict__ xbase,
                      const float* __restrict__ RW1g,
                      const float* __restrict__ uA1buf,
                      const float* __restrict__ A1w,
                      const float* __restrict__ A2w, const float* __restrict__ A2b,
                      const float* __restrict__ A3w, const float* __restrict__ A3b,
                      const int* __restrict__ item_hist,
                      const int* __restrict__ rating_hist,
                      const void* __restrict__ item_mask,
                      const int* __restrict__ flagp,
                      const int* __restrict__ aUid,
                      const int* __restrict__ nActp,
                      float* __restrict__ hvecbuf) {
  __shared__ float sA1a[64][64], sA2[64][64];
  __shared__ float xls[64][64];
  __shared__ float h1w[4][8][64];
  __shared__ float red[4][64], logit[64], alpha[64];
  __shared__ float sA2b[64], sA3w[64];
  __shared__ float sA3b;
  __shared__ int cih[64], crt[64], nact_s;
  const int tid = threadIdx.x, lane = tid & 63, w = tid >> 6;
  const int mode = flagp[0];
  for (int i = tid; i < 4096; i += 256) {
    sA1a[i >> 6][i & 63] = A1w[i];
    sA2[i >> 6][i & 63] = A2w[i];
  }
  if (tid < 64) { sA2b[tid] = A2b[tid]; sA3w[tid] = A3w[tid]; }
  if (tid == 0) sA3b = A3b[0];
  const int nA = nActp[0];
  __syncthreads();

  for (int idx = blockIdx.x; idx < nA; idx += gridDim.x) {
    const long uid = aUid[idx];
    if (w == 0) {
      long base = uid * 64;
      bool m = mread(item_mask, base + lane, mode);
      unsigned long long bal = __ballot(m);
      int pos = __popcll(bal & ((1ull << lane) - 1ull));
      if (m) { cih[pos] = item_hist[base + lane]; crt[pos] = rating_hist[base + lane]; }
      if (lane == 0) nact_s = (int)__popcll(bal);
    }
    const float ubase = uA1buf[(long)idx * 64 + lane];
    __syncthreads();
    const int nact = nact_s;
    for (int j = w; j < nact; j += 4) {
      long it = cih[j];
      int rt = crt[j];
      xls[j][lane] = fmaxf(xbase[it * 64 + lane] + RW1g[rt * 64 + lane], 0.0f);
    }
    __syncthreads();

    const int nch = (nact > 32) ? 2 : 1;
    for (int c = 0; c < nch; ++c) {
      const int j0 = c * 32 + w * 8;
      // att1: h1 = relu(x @ A1a + uA1)
      float acc[8];
#pragma unroll
      for (int r = 0; r < 8; ++r) acc[r] = ubase;
      for (int k = 0; k < 64; k += 4) {
        float wv0 = sA1a[k][lane], wv1 = sA1a[k + 1][lane];
        float wv2 = sA1a[k + 2][lane], wv3 = sA1a[k + 3][lane];
#pragma unroll
        for (int r = 0; r < 8; ++r) {
          const float4 xv = *(const float4*)(&xls[j0 + r][k]);
          acc[r] = fmaf(xv.x, wv0, acc[r]);
          acc[r] = fmaf(xv.y, wv1, acc[r]);
          acc[r] = fmaf(xv.z, wv2, acc[r]);
          acc[r] = fmaf(xv.w, wv3, acc[r]);
        }
      }
#pragma unroll
      for (int r = 0; r < 8; ++r) h1w[w][r][lane] = fmaxf(acc[r], 0.0f);
      __syncthreads();
      // att2 + logit on the same 8 rows
      float acc2[8];
#pragma unroll
      for (int r = 0; r < 8; ++r) acc2[r] = sA2b[lane];
      for (int k = 0; k < 64; k += 4) {
        float wv0 = sA2[k][lane], wv1 = sA2[k + 1][lane];
        float wv2 = sA2[k + 2][lane], wv3 = sA2[k + 3][lane];
#pragma unroll
        for (int r = 0; r < 8; ++r) {
          const float4 hv = *(const float4*)(&h1w[w][r][k]);
          acc2[r] = fmaf(hv.x, wv0, acc2[r]);
          acc2[r] = fmaf(hv.y, wv1, acc2[r]);
          acc2[r] = fmaf(hv.z, wv2, acc2[r]);
          acc2[r] = fmaf(hv.w, wv3, acc2[r]);
        }
      }
#pragma unroll
      for (int r = 0; r < 8; ++r) {
        float p = fmaxf(acc2[r], 0.0f) * sA3w[lane];
        p = wsum(p);
        if (lane == 0 && (j0 + r) < nact) logit[j0 + r] = p + sA3b;
      }
      __syncthreads();
    }

    if (w == 0) {
      float lv = (lane < nact) ? logit[lane] : -1e30f;
      float mx = wmax(lv);
      float e = (lane < nact) ? __expf(lv - mx) : 0.0f;
      float s = wsum(e);
      alpha[lane] = e / s;
    }
    __syncthreads();
    float acch = 0.0f;
    for (int j = w; j < nact; j += 4) acch = fmaf(alpha[j], xls[j][lane], acch);
    red[w][lane] = acch;
    __syncthreads();
    if (tid < 64)
      hvecbuf[(long)idx * 64 + tid] = red[0][tid] + red[1][tid] + red[2][tid] + red[3][tid];
    __syncthreads();
  }
}

// ---------------------------------------------------------------------------
// K6: hI2buf[idx] = relu(hvecbuf[idx] @ i_ln2 + b).  64 rows / block.
// ---------------------------------------------------------------------------
__global__ __launch_bounds__(256, 2)
void hI2_kernel(const float* __restrict__ hvecbuf,
                const float* __restrict__ W2w, const float* __restrict__ W2b,
                const int* __restrict__ nActp, float* __restrict__ hI2buf) {
  const int tid = threadIdx.x, lane = tid & 63, w = tid >> 6;
  const int i0 = blockIdx.x * 64;
  const int nA = nActp[0];
  if (i0 >= nA) return;
  __shared__ float sW[64][64], sX[64][64];
  __shared__ float sb[64];
  for (int i = tid; i < 4096; i += 256) sW[i >> 6][i & 63] = W2w[i];
  if (tid < 64) sb[tid] = W2b[tid];
  for (int i = tid; i < 4096; i += 256) {
    int r = i >> 6, c = i & 63;
    sX[r][c] = (i0 + r < nA) ? hvecbuf[(long)(i0 + r) * 64 + c] : 0.0f;
  }
  __syncthreads();
  float acc[16];
#pragma unroll
  for (int r = 0; r < 16; ++r) acc[r] = sb[lane];
  for (int k = 0; k < 64; k += 4) {
    float wv0 = sW[k][lane], wv1 = sW[k + 1][lane];
    float wv2 = sW[k + 2][lane], wv3 = sW[k + 3][lane];
#pragma unroll
    for (int r = 0; r < 16; ++r) {
      const float4 xv = *(const float4*)(&sX[w * 16 + r][k]);
      acc[r] = fmaf(xv.x, wv0, acc[r]);
      acc[r] = fmaf(xv.y, wv1, acc[r]);
      acc[r] = fmaf(xv.z, wv2, acc[r]);
      acc[r] = fmaf(xv.w, wv3, acc[r]);
    }
  }
#pragma unroll
  for (int r = 0; r < 16; ++r) {
    int row = i0 + w * 16 + r;
    if (row < nA) hI2buf[(long)row * 64 + lane] = fmaxf(acc[r], 0.0f);
  }
}

// ---------------------------------------------------------------------------
// K7: hIbuf[inst] = relu([u ; hI2] @ i_ln3 + b).  32 rows / block (k=128).
// ---------------------------------------------------------------------------
__global__ __launch_bounds__(256, 2)
void final_kernel(const float* __restrict__ hI2buf,
                  const float* __restrict__ user_w,
                  const float* __restrict__ W3w, const float* __restrict__ W3b,
                  const int* __restrict__ list, const int* __restrict__ aUid,
                  const int* __restrict__ nActp, float* __restrict__ hIbuf) {
  const int tid = threadIdx.x, lane = tid & 63, w = tid >> 6;
  const int i0 = blockIdx.x * 32;
  const int nA = nActp[0];
  if (i0 >= nA) return;
  __shared__ float sW[128][64];
  __shared__ float sX[32][128];
  __shared__ float sb[64];
  __shared__ int sUid[32], sInst[32];
  for (int i = tid; i < 8192; i += 256) sW[i >> 6][i & 63] = W3w[i];
  if (tid < 64) sb[tid] = W3b[tid];
  if (tid < 32) {
    bool ok = (i0 + tid) < nA;
    sUid[tid] = ok ? aUid[i0 + tid] : 0;
    sInst[tid] = ok ? list[i0 + tid] : 0;
  }
  __syncthreads();
  for (int i = tid; i < 4096; i += 256) {
    int r = i >> 7, c = i & 127;
    sX[r][c] = (c < 64) ? user_w[(long)sUid[r] * 64 + c]
                        : hI2buf[(long)(i0 + r) * 64 + (c - 64)];
  }
  __syncthreads();
  float acc[8];
#pragma unroll
  for (int r = 0; r < 8; ++r) acc[r] = sb[lane];
  for (int k = 0; k < 128; k += 4) {
    float wv0 = sW[k][lane], wv1 = sW[k + 1][lane];
    float wv2 = sW[k + 2][lane], wv3 = sW[k + 3][lane];
#pragma unroll
    for (int r = 0; r < 8; ++r) {
      const float4 xv = *(const float4*)(&sX[w * 8 + r][k]);
      acc[r] = fmaf(xv.x, wv0, acc[r]);
      acc[r] = fmaf(xv.y, wv1, acc[r]);
      acc[r] = fmaf(xv.z, wv2, acc[r]);
      acc[r] = fmaf(xv.w, wv3, acc[r]);
    }
  }
#pragma unroll
  for (int r = 0; r < 8; ++r) {
    int row = i0 + w * 8 + r;
    if (row < nA)
      hIbuf[(long)sInst[w * 8 + r] * 64 + lane] = fmaxf(acc[r], 0.0f);
  }
}

// ---------------------------------------------------------------------------
// K8: social aggregation + final MLP. One block per batch element.
// Streams s_att1[0:64]/s_att2 from LDS; matvec weights from global (small).
// ---------------------------------------------------------------------------
__global__ __launch_bounds__(256, 2)
void social_kernel(const float* __restrict__ user_w,
                   const float* __restrict__ hIbuf,
                   const float* __restrict__ A1w, const float* __restrict__ A1b,
                   const float* __restrict__ A2w, const float* __restrict__ A2b,
                   const float* __restrict__ A3w, const float* __restrict__ A3b,
                   const float* __restrict__ L1w, const float* __restrict__ L1b,
                   const float* __restrict__ L2w, const float* __restrict__ L2b,
                   const float* __restrict__ L3w, const float* __restrict__ L3b,
                   const int* __restrict__ nodes,
                   const void* __restrict__ social_mask,
                   const int* __restrict__ flagp,
                   float* __restrict__ out) {
  __shared__ float sA1a[64][64], sA2[64][64];
  __shared__ float hv[32][64];
  __shared__ float h1w[4][8][64];
  __shared__ float uvec[64], uA1[64], selfv[64], vecA[64], vecB[64];
  __shared__ float red[4][64], logit[32], alpha[32];
  __shared__ float sA2b[64], sA3w[64];
  __shared__ float sA3b;
  __shared__ int cslot[32], nval_s;
  const int tid = threadIdx.x, lane = tid & 63, w = tid >> 6;
  const int mode = flagp[0];
  const int b = blockIdx.x;
  const long uid = nodes[b];

  for (int i = tid; i < 4096; i += 256) {
    sA1a[i >> 6][i & 63] = A1w[i];
    sA2[i >> 6][i & 63] = A2w[i];
  }
  if (tid == 0) sA3b = A3b[0];
  if (w == 0) {
    bool m = false;
    if (lane < 32) m = mread(social_mask, uid * LSS + lane, mode);
    unsigned long long bal = __ballot(m);
    int pos = __popcll(bal & ((1ull << lane) - 1ull));
    if (m) cslot[pos] = lane;
    if (lane == 0) nval_s = (int)__popcll(bal);
  } else if (w == 1) {
    uvec[lane] = user_w[uid * 64 + lane];
    sA2b[lane] = A2b[lane];
  } else if (w == 2) {
    selfv[lane] = hIbuf[(long)b * 64 + lane];
    sA3w[lane] = A3w[lane];
  }
  __syncthreads();
  const int nval = nval_s;

  // uA1 partial (global A1w rows 64..127) + gather neighbor hI rows
  {
    float acc = 0.0f;
#pragma unroll
    for (int kk = 0; kk < 16; ++kk) {
      int k = w * 16 + kk;
      acc = fmaf(uvec[k], A1w[(64 + k) * 64 + lane], acc);
    }
    red[w][lane] = acc;
  }
  for (int j = w; j < nval; j += 4)
    hv[j][lane] = hIbuf[(512L + (long)b * 32 + cslot[j]) * 64 + lane];
  __syncthreads();
  if (tid < 64)
    uA1[tid] = red[0][tid] + red[1][tid] + red[2][tid] + red[3][tid] + A1b[tid];
  __syncthreads();

  // att1 (8 rows per wave)
  {
    const float base = uA1[lane];
    float acc[8];
#pragma unroll
    for (int r = 0; r < 8; ++r) acc[r] = base;
    for (int k = 0; k < 64; k += 4) {
      float wv0 = sA1a[k][lane], wv1 = sA1a[k + 1][lane];
      float wv2 = sA1a[k + 2][lane], wv3 = sA1a[k + 3][lane];
#pragma unroll
      for (int r = 0; r < 8; ++r) {
        const float4 xv = *(const float4*)(&hv[w * 8 + r][k]);
        acc[r] = fmaf(xv.x, wv0, acc[r]);
        acc[r] = fmaf(xv.y, wv1, acc[r]);
        acc[r] = fmaf(xv.z, wv2, acc[r]);
        acc[r] = fmaf(xv.w, wv3, acc[r]);
      }
    }
#pragma unroll
    for (int r = 0; r < 8; ++r) h1w[w][r][lane] = fmaxf(acc[r], 0.0f);
  }
  __syncthreads();

  // att2 + logit
  {
    float acc2[8];
#pragma unroll
    for (int r = 0; r < 8; ++r) acc2[r] = sA2b[lane];
    for (int k = 0; k < 64; k += 4) {
      float wv0 = sA2[k][lane], wv1 = sA2[k + 1][lane];
      float wv2 = sA2[k + 2][lane], wv3 = sA2[k + 3][lane];
#pragma unroll
      for (int r = 0; r < 8; ++r) {
        const float4 hvv = *(const float4*)(&h1w[w][r][k]);
        acc2[r] = fmaf(hvv.x, wv0, acc2[r]);
        acc2[r] = fmaf(hvv.y, wv1, acc2[r]);
        acc2[r] = fmaf(hvv.z, wv2, acc2[r]);
        acc2[r] = fmaf(hvv.w, wv3, acc2[r]);
      }
    }
#pragma unroll
    for (int r = 0; r < 8; ++r) {
      int j = w * 8 + r;
      float p = fmaxf(acc2[r], 0.0f) * sA3w[lane];
      p = wsum(p);
      if (lane == 0 && j < nval) logit[j] = p + sA3b;
    }
  }
  __syncthreads();

  if (w == 0) {
    float lv = (lane < nval) ? logit[lane] : -1e30f;
    float mx = wmax(lv);
    float e = (lane < nval) ? __expf(lv - mx) : 0.0f;
    float s = wsum(e);
    if (lane < 32) alpha[lane] = e / s;
  }
  __syncthreads();

  // hS
  {
    float acc = 0.0f;
    for (int j = w; j < nval; j += 4) acc = fmaf(alpha[j], hv[j][lane], acc);
    red[w][lane] = acc;
  }
  __syncthreads();
  if (tid < 64) vecA[tid] = red[0][tid] + red[1][tid] + red[2][tid] + red[3][tid];
  __syncthreads();

  // hS = relu(hS @ s_ln1 + b)
  {
    float acc = 0.0f;
#pragma unroll
    for (int kk = 0; kk < 16; ++kk) {
      int k = w * 16 + kk;
      acc = fmaf(vecA[k], L1w[k * 64 + lane], acc);
    }
    red[w][lane] = acc;
  }
  __syncthreads();
  if (tid < 64)
    vecB[tid] = fmaxf(red[0][tid] + red[1][tid] + red[2][tid] + red[3][tid] + L1b[tid], 0.0f);
  __syncthreads();

  // f = relu([hI_self ; hS] @ s_ln2 + b)
  {
    float acc = 0.0f;
#pragma unroll
    for (int kk = 0; kk < 32; ++kk) {
      int k = w * 32 + kk;
      float xv = (k < 64) ? selfv[k] : vecB[k - 64];
      acc = fmaf(xv, L2w[k * 64 + lane], acc);
    }
    red[w][lane] = acc;
  }
  __syncthreads();
  if (tid < 64)
    vecA[tid] = fmaxf(red[0][tid] + red[1][tid] + red[2][tid] + red[3][tid] + L2b[tid], 0.0f);
  __syncthreads();

  // out = relu(f @ s_ln3 + b)
  {
    float acc = 0.0f;
#pragma unroll
    for (int kk = 0; kk < 16; ++kk) {
      int k = w * 16 + kk;
      acc = fmaf(vecA[k], L3w[k * 64 + lane], acc);
    }
    red[w][lane] = acc;
  }
  __syncthreads();
  if (tid < 64)
    out[(long)b * 64 + tid] =
        fmaxf(red[0][tid] + red[1][tid] + red[2][tid] + red[3][tid] + L3b[tid], 0.0f);
}

// ---------------------------------------------------------------------------
extern "C" void kernel_launch(void* const* d_in, const int* in_sizes, int n_in,
                              void* d_out, int out_size, void* d_ws, size_t ws_size,
                              hipStream_t stream) {
  const float* user_w   = (const float*)d_in[0];
  const float* item_w   = (const float*)d_in[1];
  const float* rating_w = (const float*)d_in[2];
  const float* i_ln1_w  = (const float*)d_in[3];
  const float* i_ln1_b  = (const float*)d_in[4];
  const float* i_ln2_w  = (const float*)d_in[5];
  const float* i_ln2_b  = (const float*)d_in[6];
  const float* i_ln3_w  = (const float*)d_in[7];
  const float* i_ln3_b  = (const float*)d_in[8];
  const float* i_att1_w = (const float*)d_in[9];
  const float* i_att1_b = (const float*)d_in[10];
  const float* i_att2_w = (const float*)d_in[11];
  const float* i_att2_b = (const float*)d_in[12];
  const float* i_att3_w = (const float*)d_in[13];
  const float* i_att3_b = (const float*)d_in[14];
  const float* s_ln1_w  = (const float*)d_in[15];
  const float* s_ln1_b  = (const float*)d_in[16];
  const float* s_ln2_w  = (const float*)d_in[17];
  const float* s_ln2_b  = (const float*)d_in[18];
  const float* s_ln3_w  = (const float*)d_in[19];
  const float* s_ln3_b  = (const float*)d_in[20];
  const float* s_att1_w = (const float*)d_in[21];
  const float* s_att1_b = (const float*)d_in[22];
  const float* s_att2_w = (const float*)d_in[23];
  const float* s_att2_b = (const float*)d_in[24];
  const float* s_att3_w = (const float*)d_in[25];
  const float* s_att3_b = (const float*)d_in[26];
  const int*  nodes       = (const int*)d_in[27];
  const int*  social_hist = (const int*)d_in[28];
  const void* social_mask = d_in[29];
  const int*  item_hist   = (const int*)d_in[30];
  const int*  rating_hist = (const int*)d_in[31];
  const void* item_mask   = d_in[32];

  // workspace layout (bytes)
  char* ws = (char*)d_ws;
  int*   flag    = (int*)(ws + 0);                 // 256
  int*   counter = (int*)(ws + 256);               // 256
  int*   list    = (int*)(ws + 512);               // NT*4 = 67584
  int*   aUid    = (int*)(ws + 68096);             // 67584
  float* uA1buf  = (float*)(ws + 135680);          // NT*64*4 = 4325376 (also hI2buf)
  float* hI2buf  = uA1buf;                         // alias: uA1 dead before K6
  float* hvecbuf = (float*)(ws + 4461056);         // 4325376 (also hIbuf)
  float* hIbuf   = hvecbuf;                        // alias: hvec dead before K7
  float* xbase   = (float*)(ws + 8786432);         // 50000*64*4 = 12800000
  float* RW1g    = (float*)(ws + 21586432);        // 5*64*4

  hipMemsetAsync(counter, 0, 4, stream);
  detect_mask_kernel<<<1, 256, 0, stream>>>((const unsigned int*)social_mask, flag);
  pre_rw_kernel<<<1, 320, 0, stream>>>(rating_w, i_ln1_w, i_ln1_b, RW1g);
  pre_xbase_kernel<<<(NII + 31) / 32, 256, 0, stream>>>(item_w, i_ln1_w, xbase);
  build_active_kernel<<<NT / 256, 256, 0, stream>>>(
      nodes, social_hist, social_mask, flag, counter, list, aUid);
  uA1_kernel<<<NT / 64, 256, 0, stream>>>(user_w, i_att1_w, i_att1_b, aUid, counter, uA1buf);
  core_attn_kernel<<<512, 256, 0, stream>>>(
      xbase, RW1g, uA1buf, i_att1_w, i_att2_w, i_att2_b, i_att3_w, i_att3_b,
      item_hist, rating_hist, item_mask, flag, aUid, counter, hvecbuf);
  hI2_kernel<<<NT / 64, 256, 0, stream>>>(hvecbuf, i_ln2_w, i_ln2_b, counter, hI2buf);
  final_kernel<<<NT / 32, 256, 0, stream>>>(hI2buf, user_w, i_ln3_w, i_ln3_b,
                                            list, aUid, counter, hIbuf);
  social_kernel<<<BB, 256, 0, stream>>>(
      user_w, hIbuf,
      s_att1_w, s_att1_b, s_att2_w, s_att2_b, s_att3_w, s_att3_b,
      s_ln1_w, s_ln1_b, s_ln2_w, s_ln2_b, s_ln3_w, s_ln3_b,
      nodes, social_mask, flag, (float*)d_out);
}